// Round 10
// baseline (593.381 us; speedup 1.0000x reference)
//
#include <hip/hip_runtime.h>

typedef unsigned short u16;
typedef unsigned int   u32;
typedef _Float16 half8 __attribute__((ext_vector_type(8)));
typedef _Float16 half2v __attribute__((ext_vector_type(2)));
typedef float    f32x4 __attribute__((ext_vector_type(4)));
typedef unsigned int u32x4 __attribute__((ext_vector_type(4)));
typedef int      i32x2 __attribute__((ext_vector_type(2)));

#define NN 50000
#define EE 800000
#define SCALE 0.17677669529663687f
#define NB 49   // ceil(50000/1024)

// workspace layout (bytes)
#define O_WNODET   0ul          // 1536*128 f16
#define O_WFT      393216ul     // 128*512 f16
#define O_WF1      524288ul     // 128*128 f32
#define O_WF3      589824ul     // 128*128 f32
#define O_HIST     655360ul     // 50000 i32
#define O_BSUM     855360ul     // 49 i32 (inside HIST pad region)
#define O_BOFF     855616ul     // 49 i32
#define O_OFF      856064ul     // 50000 i32 (block-local exclusive scan)
#define O_CUR      1056768ul
#define O_PERM     1257472ul    // 800000 int2
#define O_NODEQ    7657472ul    // 50000*896 f16 = 89.6 MB (dst-side: q1,q2,qa,r1,r2,ra,resid)
#define O_NODEKV   97257472ul   // 50000*640 f16 = 64 MB (src-side: k1,k2,ka,vd,va)
#define O_G        161257472ul  // 50000*512 f16 ; ALSO reused as xh (50000*128 f16)
                                // during gemm_node — Gf is written only later by attn.

__device__ __forceinline__ float fin(float x){
  return (x == x && fabsf(x) < 3e38f) ? x : 0.f;
}
__device__ __forceinline__ u32 packh(float a, float b){
  union{ u32 u; _Float16 h[2]; } cv; cv.h[0]=(_Float16)a; cv.h[1]=(_Float16)b; return cv.u;
}
union H2U { u32 u; half2v h; };
__device__ __forceinline__ half2v h2(u32 u){ H2U c; c.u=u; return c.h; }

// non-temporal (no-allocate) loads for read-once streams
__device__ __forceinline__ u32x4 ntl4(const u32* p){
  return __builtin_nontemporal_load((const u32x4*)p);
}
__device__ __forceinline__ f32x4 ntlf4(const float* p){
  return __builtin_nontemporal_load((const f32x4*)p);
}
__device__ __forceinline__ i32x2 ntl2(const i32x2* p){
  return __builtin_nontemporal_load(p);
}

// ---------------- x -> f16 cast (once) + zero hist/cur (folds 2 memsets) ----------------
__global__ __launch_bounds__(256) void xcast(const float* __restrict__ x,
                                             _Float16* __restrict__ xh,
                                             int* __restrict__ hist, int* __restrict__ cur)
{
  int i = blockIdx.x*256 + threadIdx.x;       // 800000 chunks of 8
  if (i < NN){ hist[i] = 0; cur[i] = 0; }
  size_t b = (size_t)i * 8;
  float4 v0 = *(const float4*)(x + b);
  float4 v1 = *(const float4*)(x + b + 4);
  half8 h;
  h[0]=(_Float16)v0.x; h[1]=(_Float16)v0.y; h[2]=(_Float16)v0.z; h[3]=(_Float16)v0.w;
  h[4]=(_Float16)v1.x; h[5]=(_Float16)v1.y; h[6]=(_Float16)v1.z; h[7]=(_Float16)v1.w;
  *(half8*)(xh + b) = h;
}

// ---------------- weight prep ----------------
__global__ __launch_bounds__(256) void prep1(
    const float* __restrict__ Wq1, const float* __restrict__ Wq2, const float* __restrict__ Wqa,
    const float* __restrict__ Wk1, const float* __restrict__ Wk2, const float* __restrict__ Wka,
    const float* __restrict__ Wvd, const float* __restrict__ Wva, const float* __restrict__ Win,
    const float* __restrict__ Wkr1, const float* __restrict__ Wkr2, const float* __restrict__ Wkra,
    const float* __restrict__ Wproj, const float* __restrict__ Woutd, const float* __restrict__ Wouta,
    _Float16* __restrict__ WnodeT, float* __restrict__ Wf1, float* __restrict__ Wf3)
{
  int job = blockIdx.x*256 + threadIdx.x;
  if (job < 1536*128) {
    int n = job >> 7, kk = job & 127;
    int slot = n >> 7, o = n & 127;
    float val;
    if (slot==3 || slot==4 || slot==5) {
      const float* Wkr = (slot==3)?Wkr1:(slot==4)?Wkr2:Wkra;
      const float* Wq  = (slot==3)?Wq1 :(slot==4)?Wq2 :Wqa;
      int h=o>>5, j=o&31;
      float s=0.f;
      for (int c=0;c<32;c++)
        s += Wkr[(h*32+c)*32 + j] * Wq[(h*32+c)*128 + kk];
      val = s;
    } else {
      const float* W = (slot==0)?Wq1:(slot==1)?Wq2:(slot==2)?Wqa:
                       (slot==6)?Wk1:(slot==7)?Wk2:(slot==8)?Wka:
                       (slot==9)?Wvd:(slot==10)?Wva:Win;
      val = W[o*128 + kk];
    }
    WnodeT[n*128 + kk] = (_Float16)fin(val);
  } else {
    int idx = job - 1536*128;
    int which = idx >> 14;
    int r = idx & 16383;
    int o = r >> 7, v = r & 127;
    const float* Wout = which ? Wouta : Woutd;
    float s=0.f;
    for (int u=0;u<128;u++)
      s += Wproj[o*256 + which*128 + u] * Wout[u*128 + v];
    (which?Wf3:Wf1)[o*128+v] = fin(s);
  }
}

__global__ __launch_bounds__(256) void prep2(
    const float* __restrict__ Wf1, const float* __restrict__ Wf3,
    const float* __restrict__ Wvrd, const float* __restrict__ Wvra,
    _Float16* __restrict__ WfT)
{
  int job = blockIdx.x*256 + threadIdx.x;
  int o = job >> 9, kk = job & 511;
  int seg = kk >> 7, v = kk & 127;
  float val;
  if (seg==0) val = Wf1[o*128+v];
  else if (seg==2) val = Wf3[o*128+v];
  else {
    const float* Wf = (seg==1)?Wf1:Wf3;
    const float* Wv = (seg==1)?Wvrd:Wvra;
    int h=v>>5, j=v&31; float s=0.f;
    for (int c=0;c<32;c++)
      s += Wf[o*128 + h*32 + c] * Wv[(h*32+c)*32 + j];
    val = s;
  }
  WfT[o*512 + kk] = (_Float16)fin(val);
}

// ---------------- node GEMM v3: LDS-free ----------------
// 1 wave = 32-row x 128-col output strip, K=128 fully unrolled.
// A (xh, L3-resident) and B (WnodeT, 384KB L2-hot) MFMA fragments are loaded
// DIRECTLY from global. No barriers in the main loop; independent waves hide
// latency. LDS (8.7KB) only for the store epilogue. grid = (1563, 12).
__global__ __launch_bounds__(64, 4) void gemm_node(
    const _Float16* __restrict__ xh, const _Float16* __restrict__ WnodeT,
    const float* __restrict__ b_in,
    _Float16* __restrict__ nodeQ, _Float16* __restrict__ nodeKV)
{
  __shared__ _Float16 S[32*136];
  int m0 = blockIdx.x * 32;
  int slot = blockIdx.y;
  int n0 = slot * 128;
  int lane = threadIdx.x & 63;
  int lm = lane & 15, lq = lane >> 4;

  f32x4 acc[2][8];
  #pragma unroll
  for (int i=0;i<2;i++)
    #pragma unroll
    for (int j=0;j<8;j++) acc[i][j] = (f32x4){0.f,0.f,0.f,0.f};

  int r0 = m0 + lm, r1 = m0 + 16 + lm;
  bool ok0 = r0 < NN, ok1 = r1 < NN;
  _Float16 zmask0 = ok0 ? (_Float16)1.f : (_Float16)0.f;
  _Float16 zmask1 = ok1 ? (_Float16)1.f : (_Float16)0.f;
  const _Float16* pa0 = xh + (size_t)(ok0 ? r0 : 0)*128 + lq*8;
  const _Float16* pa1 = xh + (size_t)(ok1 ? r1 : 0)*128 + lq*8;
  const _Float16* pb  = WnodeT + (size_t)(n0 + lm)*128 + lq*8;

  #pragma unroll
  for (int ks=0; ks<4; ks++){
    int kk0 = ks*32;
    half8 a0 = *(const half8*)(pa0 + kk0);
    half8 a1 = *(const half8*)(pa1 + kk0);
    #pragma unroll
    for (int j=0;j<8;j++){ a0[j] = a0[j]*zmask0; a1[j] = a1[j]*zmask1; }
    #pragma unroll
    for (int ct=0; ct<8; ct++){
      half8 b = *(const half8*)(pb + (size_t)ct*16*128 + kk0);
      acc[0][ct] = __builtin_amdgcn_mfma_f32_16x16x32_f16(a0, b, acc[0][ct], 0,0,0);
      acc[1][ct] = __builtin_amdgcn_mfma_f32_16x16x32_f16(a1, b, acc[1][ct], 0,0,0);
    }
  }

  // epilogue: LDS transpose then coalesced half8 stores
  #pragma unroll
  for (int rt=0; rt<2; rt++){
    #pragma unroll
    for (int reg=0; reg<4; reg++){
      int row = rt*16 + lq*4 + reg;
      #pragma unroll
      for (int ct=0; ct<8; ct++){
        int col = ct*16 + lm;
        float bias = (slot == 11) ? b_in[col] : 0.f;
        S[row*136 + col] = (_Float16)fin(acc[rt][ct][reg] + bias);
      }
    }
  }
  __syncthreads();
  #pragma unroll
  for (int i=0;i<8;i++){
    int idx = (int)threadIdx.x + i*64;
    int row = idx >> 4, c8 = (idx & 15)*8;
    int grow = m0 + row;
    if (grow < NN){
      half8 v = *(half8*)&S[row*136 + c8];
      _Float16* dst = (slot < 6)  ? nodeQ  + (size_t)grow*896 + slot*128 + c8
                    : (slot < 11) ? nodeKV + (size_t)grow*640 + (slot-6)*128 + c8
                                  : nodeQ  + (size_t)grow*896 + 768 + c8;
      *(half8*)dst = v;
    }
  }
}

// ---------------- counting sort by dst ----------------
__global__ __launch_bounds__(256) void hist_k(const int* __restrict__ ei, int* __restrict__ hist){
  int e = blockIdx.x*256 + threadIdx.x;
  int d = ei[EE + e];
  if ((unsigned)d < (unsigned)NN) atomicAdd(&hist[d], 1);
}

__global__ __launch_bounds__(1024) void scan1(const int* __restrict__ hist,
                                              int* __restrict__ loc, int* __restrict__ bsum){
  __shared__ int buf[1024];
  int i = blockIdx.x*1024 + threadIdx.x;
  int v = (i < NN) ? hist[i] : 0;
  buf[threadIdx.x] = v;
  __syncthreads();
  int xv = v;
  for (int s = 1; s < 1024; s <<= 1){
    int t = 0;
    if ((int)threadIdx.x >= s) t = buf[threadIdx.x - s];
    __syncthreads();
    xv += t;
    buf[threadIdx.x] = xv;
    __syncthreads();
  }
  if (i < NN) loc[i] = xv - v;   // block-local exclusive
  if (threadIdx.x == 1023) bsum[blockIdx.x] = xv;
}

__global__ __launch_bounds__(64) void scan2(const int* __restrict__ bsum, int* __restrict__ boff){
  int t = threadIdx.x;
  int v = (t < NB) ? bsum[t] : 0;
  int x = v;
  for (int s = 1; s < 64; s <<= 1){
    int u = __shfl_up(x, s);
    if (t >= s) x += u;
  }
  if (t < NB) boff[t] = x - v;
}

__global__ __launch_bounds__(256) void scatter_k(const int* __restrict__ ei,
                                                 const int* __restrict__ loc, const int* __restrict__ boff,
                                                 int* __restrict__ cur, int2* __restrict__ pe2){
  int e = blockIdx.x*256 + threadIdx.x;
  int d = ei[EE + e];
  if ((unsigned)d >= (unsigned)NN) return;
  int pos = loc[d] + boff[d>>10] + atomicAdd(&cur[d], 1);
  if ((unsigned)pos < (unsigned)EE) pe2[pos] = make_int2(e, ei[e]);
}

// ---------------- fused per-node attention (single dispatch) ----------------
__global__ __launch_bounds__(64, 4) void attn_k(
    const i32x2* __restrict__ pe2, const int* __restrict__ hist,
    const int* __restrict__ loc, const int* __restrict__ boff,
    const u32* __restrict__ nfQ, const u32* __restrict__ nfKV,
    const float* __restrict__ ea,
    const float* __restrict__ lamp, u32* __restrict__ G)
{
  int lane = threadIdx.x & 63;
  int node = blockIdx.x;
  if (node >= NN) return;
  int E = lane >> 4;
  int l = lane & 15;
  int h = l >> 2;
  const u32* pd = nfQ + (u32)node * 448u;

  int k = hist[node];
  if (k < 0) k = 0;
  if (k > 64) k = 64;               // Poisson(16): max ~45; guards OOB/hangs
  int o = loc[node] + boff[node>>10];
  if (o < 0) o = 0;

  // preload the node's pe2 slice: lane i holds entry i (clamped), coalesced 8B/lane
  int pe_e = 0, pe_s = 0;
  if (k > 0){
    int idxl = (lane < k) ? lane : (k-1);
    i32x2 pl = ntl2(&pe2[o + idxl]);
    pe_e = pl[0]; pe_s = pl[1];
  }

  H2U q1[4], q2[4], qa[4], r1[4], r2[4], ra[4];
  {
    u32x4 a = ntl4(pd +        l*4);
    u32x4 b = ntl4(pd +  64 + l*4);
    u32x4 c = ntl4(pd + 128 + l*4);
    q1[0].u=a[0]; q1[1].u=a[1]; q1[2].u=a[2]; q1[3].u=a[3];
    q2[0].u=b[0]; q2[1].u=b[1]; q2[2].u=b[2]; q2[3].u=b[3];
    qa[0].u=c[0]; qa[1].u=c[1]; qa[2].u=c[2]; qa[3].u=c[3];
    int rb = h*16 + (l&3)*4;
    u32x4 d = ntl4(pd + 192 + rb);
    u32x4 e = ntl4(pd + 256 + rb);
    u32x4 f = ntl4(pd + 320 + rb);
    r1[0].u=d[0]; r1[1].u=d[1]; r1[2].u=d[2]; r1[3].u=d[3];
    r2[0].u=e[0]; r2[1].u=e[1]; r2[2].u=e[2]; r2[3].u=e[3];
    ra[0].u=f[0]; ra[1].u=f[1]; ra[2].u=f[2]; ra[3].u=f[3];
  }

  H2U s1v[4], s2v[4], sav[4], s1e[4], s2e[4], sae[4];
  #pragma unroll
  for (int t=0;t<4;t++){ s1v[t].u=0; s2v[t].u=0; sav[t].u=0; s1e[t].u=0; s2e[t].u=0; sae[t].u=0; }
  float z1=0.f, z2=0.f, za=0.f;

  int iters = (k + 3) >> 2;
  for (int it=0; it<iters; it++){
    int eidx = it*4 + E;
    bool valid = eidx < k;
    int sn = __shfl(pe_s, eidx);
    int ee = __shfl(pe_e, eidx);
    if (!valid){ sn = 0; ee = 0; }
    if ((unsigned)sn >= (unsigned)NN) sn = 0;
    if ((unsigned)ee >= (unsigned)EE) ee = 0;
    const u32* ps = nfKV + (u32)sn * 320u + (u32)(l*4);
    u32x4 K1 = *(const u32x4*)(ps);
    u32x4 K2 = *(const u32x4*)(ps + 64);
    u32x4 KA = *(const u32x4*)(ps + 128);
    u32x4 VD = *(const u32x4*)(ps + 192);
    u32x4 VA = *(const u32x4*)(ps + 256);
    f32x4 ef0 = ntlf4(ea + (size_t)ee*32 + (l&3)*8);
    f32x4 ef1 = ntlf4(ea + (size_t)ee*32 + (l&3)*8 + 4);
    half2v e0 = {(_Float16)ef0[0], (_Float16)ef0[1]};
    half2v e1 = {(_Float16)ef0[2], (_Float16)ef0[3]};
    half2v e2 = {(_Float16)ef1[0], (_Float16)ef1[1]};
    half2v e3 = {(_Float16)ef1[2], (_Float16)ef1[3]};

    half2v p1h = q1[0].h*h2(K1[0]) + q1[1].h*h2(K1[1]) + q1[2].h*h2(K1[2]) + q1[3].h*h2(K1[3])
               + r1[0].h*e0 + r1[1].h*e1 + r1[2].h*e2 + r1[3].h*e3;
    half2v p2h = q2[0].h*h2(K2[0]) + q2[1].h*h2(K2[1]) + q2[2].h*h2(K2[2]) + q2[3].h*h2(K2[3])
               + r2[0].h*e0 + r2[1].h*e1 + r2[2].h*e2 + r2[3].h*e3;
    half2v pah = qa[0].h*h2(KA[0]) + qa[1].h*h2(KA[1]) + qa[2].h*h2(KA[2]) + qa[3].h*h2(KA[3])
               + ra[0].h*e0 + ra[1].h*e1 + ra[2].h*e2 + ra[3].h*e3;

    // reduce over the 4 lanes of this head (xor 1,2)
    H2U c1, c2, c3, t;
    c1.h = p1h; c2.h = p2h; c3.h = pah;
    t.u = __shfl_xor(c1.u, 1); c1.h += t.h;
    t.u = __shfl_xor(c2.u, 1); c2.h += t.h;
    t.u = __shfl_xor(c3.u, 1); c3.h += t.h;
    t.u = __shfl_xor(c1.u, 2); c1.h += t.h;
    t.u = __shfl_xor(c2.u, 2); c2.h += t.h;
    t.u = __shfl_xor(c3.u, 2); c3.h += t.h;
    float p1 = (float)c1.h[0] + (float)c1.h[1];
    float p2 = (float)c2.h[0] + (float)c2.h[1];
    float pa = (float)c3.h[0] + (float)c3.h[1];

    float w1 = valid ? __expf(p1*SCALE) : 0.f;
    float w2 = valid ? __expf(p2*SCALE) : 0.f;
    float wa = valid ? __expf(pa*SCALE) : 0.f;
    _Float16 w1f = (_Float16)w1, w2f = (_Float16)w2, waf = (_Float16)wa;
    half2v w1h = {w1f, w1f}, w2h = {w2f, w2f}, wah = {waf, waf};

    s1v[0].h += w1h*h2(VD[0]); s1v[1].h += w1h*h2(VD[1]); s1v[2].h += w1h*h2(VD[2]); s1v[3].h += w1h*h2(VD[3]);
    s2v[0].h += w2h*h2(VD[0]); s2v[1].h += w2h*h2(VD[1]); s2v[2].h += w2h*h2(VD[2]); s2v[3].h += w2h*h2(VD[3]);
    sav[0].h += wah*h2(VA[0]); sav[1].h += wah*h2(VA[1]); sav[2].h += wah*h2(VA[2]); sav[3].h += wah*h2(VA[3]);
    s1e[0].h += w1h*e0; s1e[1].h += w1h*e1; s1e[2].h += w1h*e2; s1e[3].h += w1h*e3;
    s2e[0].h += w2h*e0; s2e[1].h += w2h*e1; s2e[2].h += w2h*e2; s2e[3].h += w2h*e3;
    sae[0].h += wah*e0; sae[1].h += wah*e1; sae[2].h += wah*e2; sae[3].h += wah*e3;
    z1 += w1; z2 += w2; za += wa;
  }

  // cross-slot reduction (xor 16, 32)
  #pragma unroll
  for (int s=16; s<=32; s<<=1){
    H2U t;
    #pragma unroll
    for (int j=0;j<4;j++){
      t.u = __shfl_xor(s1v[j].u, s); s1v[j].h += t.h;
      t.u = __shfl_xor(s2v[j].u, s); s2v[j].h += t.h;
      t.u = __shfl_xor(sav[j].u, s); sav[j].h += t.h;
      t.u = __shfl_xor(s1e[j].u, s); s1e[j].h += t.h;
      t.u = __shfl_xor(s2e[j].u, s); s2e[j].h += t.h;
      t.u = __shfl_xor(sae[j].u, s); sae[j].h += t.h;
    }
    z1 += __shfl_xor(z1, s); z2 += __shfl_xor(z2, s); za += __shfl_xor(za, s);
  }

  if (E == 0){
    float lamv = lamp[0];
    float i1 = 1.f/(z1+1e-16f), i2 = 1.f/(z2+1e-16f), ia = 1.f/(za+1e-16f);
    u32 gb = (u32)node*256u;
    int rb = h*16 + (l&3)*4;
    #pragma unroll
    for (int t=0;t<4;t++){
      float d0 = fin((float)s1v[t].h[0]*i1 - lamv*((float)s2v[t].h[0]*i2));
      float d1 = fin((float)s1v[t].h[1]*i1 - lamv*((float)s2v[t].h[1]*i2));
      G[gb + l*4 + t] = packh(d0, d1);
      float e0v = fin((float)s1e[t].h[0]*i1 - lamv*((float)s2e[t].h[0]*i2));
      float e1v = fin((float)s1e[t].h[1]*i1 - lamv*((float)s2e[t].h[1]*i2));
      G[gb + 64 + rb + t] = packh(e0v, e1v);
      G[gb + 128 + l*4 + t] = packh(fin((float)sav[t].h[0]*ia), fin((float)sav[t].h[1]*ia));
      G[gb + 192 + rb + t] = packh(fin((float)sae[t].h[0]*ia), fin((float)sae[t].h[1]*ia));
    }
  }
}

// ---------------- final GEMM + bias + residual + RMSNorm ----------------
// M-tile 64; epilogue stages normalized rows in LDS then stores coalesced f32x4.
__global__ __launch_bounds__(256) void gemm_final(
    const _Float16* __restrict__ Gf, const _Float16* __restrict__ WfT,
    const _Float16* __restrict__ nodeQ,
    const float* __restrict__ bproj, const float* __restrict__ rmsw,
    float* __restrict__ out)
{
  __shared__ char SS[34816];                         // As+Bs staging; epilogue f32 [64][132]
  _Float16 (*As)[72] = (_Float16(*)[72])SS;          // 64*72*2  = 9216 B
  _Float16 (*Bs)[72] = (_Float16(*)[72])(SS + 9216); // 128*72*2 = 18432 B
  float* Sf = (float*)SS;                            // 64*132*4 = 33792 B (reuse)
  __shared__ float bS[128], rS[128];
  int m0 = blockIdx.x * 64;
  int tid = threadIdx.x;
  int lane = tid & 63, wave = tid >> 6;
  int lm = lane & 15, lq = lane >> 4;
  int mbase = wave*16;
  if (tid < 128){ bS[tid] = bproj[tid]; rS[tid] = rmsw[tid]; }
  f32x4 acc[8];
  #pragma unroll
  for (int j=0;j<8;j++) acc[j] = (f32x4){0.f,0.f,0.f,0.f};

  for (int kt=0; kt<8; kt++){
    int kk0 = kt*64;
    #pragma unroll
    for (int i=0;i<2;i++){
      int c = tid + i*256;
      int row = c >> 3, kc = (c & 7) * 8;
      int grow = m0 + row;
      half8 av;
      if (grow < NN){
        av = *(const half8*)(Gf + (size_t)grow*512 + kk0 + kc);
      } else {
        #pragma unroll
        for (int j=0;j<8;j++) av[j] = (_Float16)0.f;
      }
      *(half8*)&As[row][kc] = av;
    }
    #pragma unroll
    for (int i=0;i<4;i++){
      int c = tid + i*256;
      int row = c >> 3, kc = (c & 7) * 8;
      *(half8*)&Bs[row][kc] = *(const half8*)(WfT + (size_t)row*512 + kk0 + kc);
    }
    __syncthreads();
    #pragma unroll
    for (int ks=0; ks<64; ks+=32){
      half8 a0 = *(half8*)&As[mbase + lm][ks + lq*8];
      #pragma unroll
      for (int ct=0; ct<8; ct++){
        half8 b = *(half8*)&Bs[ct*16 + lm][ks + lq*8];
        acc[ct] = __builtin_amdgcn_mfma_f32_16x16x32_f16(a0, b, acc[ct], 0,0,0);
      }
    }
    __syncthreads();
  }
  // epilogue: normalize into LDS, then coalesced f32x4 stores
  #pragma unroll
  for (int reg=0; reg<4; reg++){
    int rowl = mbase + lq*4 + reg;
    int row = m0 + rowl;
    bool ok = row < NN;
    float vals[8]; float ss = 0.f;
    #pragma unroll
    for (int ct=0; ct<8; ct++){
      int col = ct*16 + lm;
      float R = ok ? (float)nodeQ[(size_t)row*896 + 768 + col] : 0.f;
      float v = fin(acc[ct][reg] + bS[col] + R);
      vals[ct] = v; ss += v*v;
    }
    #pragma unroll
    for (int sh=1; sh<16; sh<<=1) ss += __shfl_xor(ss, sh);
    float rstd = rsqrtf(ss*(1.0f/128.f) + 1e-6f);
    #pragma unroll
    for (int ct=0; ct<8; ct++){
      int col = ct*16 + lm;
      Sf[rowl*132 + col] = fin(vals[ct]*rstd*rS[col]);
    }
  }
  __syncthreads();
  #pragma unroll
  for (int i=0;i<8;i++){
    int idx = tid + i*256;
    int rowl = idx >> 5, c4 = (idx & 31) * 4;
    int grow = m0 + rowl;
    if (grow < NN){
      f32x4 v = *(f32x4*)&Sf[rowl*132 + c4];
      *(f32x4*)(out + (size_t)grow*128 + c4) = v;
    }
  }
}

extern "C" void kernel_launch(void* const* d_in, const int* in_sizes, int n_in,
                              void* d_out, int out_size, void* d_ws, size_t ws_size,
                              hipStream_t stream)
{
  char* w = (char*)d_ws;
  _Float16* WnodeT = (_Float16*)(w + O_WNODET);
  _Float16* WfT    = (_Float16*)(w + O_WFT);
  float*    Wf1    = (float*)(w + O_WF1);
  float*    Wf3    = (float*)(w + O_WF3);
  int*      hist   = (int*)(w + O_HIST);
  int*      bsum   = (int*)(w + O_BSUM);
  int*      boff   = (int*)(w + O_BOFF);
  int*      loc    = (int*)(w + O_OFF);
  int*      cur    = (int*)(w + O_CUR);
  int2*     pe2    = (int2*)(w + O_PERM);
  _Float16* nodeQ  = (_Float16*)(w + O_NODEQ);
  _Float16* nodeKV = (_Float16*)(w + O_NODEKV);
  _Float16* Gf     = (_Float16*)(w + O_G);
  _Float16* xh     = (_Float16*)(w + O_G);   // reused region: consumed before Gf is written

  const float* x     = (const float*)d_in[0];
  const int*   ei    = (const int*)d_in[1];
  const float* ea    = (const float*)d_in[2];
  const float* Wq1   = (const float*)d_in[3];
  const float* Wq2   = (const float*)d_in[4];
  const float* Wk1   = (const float*)d_in[5];
  const float* Wk2   = (const float*)d_in[6];
  const float* Wvd   = (const float*)d_in[7];
  const float* Wkr1  = (const float*)d_in[8];
  const float* Wkr2  = (const float*)d_in[9];
  const float* Wvrd  = (const float*)d_in[10];
  const float* Woutd = (const float*)d_in[11];
  const float* lam   = (const float*)d_in[12];
  const float* Wqa   = (const float*)d_in[13];
  const float* Wka   = (const float*)d_in[14];
  const float* Wva   = (const float*)d_in[15];
  const float* Wkra  = (const float*)d_in[16];
  const float* Wvra  = (const float*)d_in[17];
  const float* Wouta = (const float*)d_in[18];
  const float* Wproj = (const float*)d_in[19];
  const float* bproj = (const float*)d_in[20];
  const float* Win   = (const float*)d_in[21];
  const float* b_in  = (const float*)d_in[22];
  const float* rmsw  = (const float*)d_in[23];

  xcast<<<3125, 256, 0, stream>>>(x, xh, hist, cur);
  prep1<<<896, 256, 0, stream>>>(Wq1,Wq2,Wqa, Wk1,Wk2,Wka, Wvd,Wva,Win,
                                 Wkr1,Wkr2,Wkra, Wproj,Woutd,Wouta,
                                 WnodeT, Wf1, Wf3);
  prep2<<<256, 256, 0, stream>>>(Wf1, Wf3, Wvrd, Wvra, WfT);
  gemm_node<<<dim3(1563,12), 64, 0, stream>>>(xh, WnodeT, b_in, nodeQ, nodeKV);
  hist_k<<<3125, 256, 0, stream>>>(ei, hist);
  scan1<<<NB, 1024, 0, stream>>>(hist, loc, bsum);
  scan2<<<1, 64, 0, stream>>>(bsum, boff);
  scatter_k<<<3125, 256, 0, stream>>>(ei, loc, boff, cur, pe2);
  attn_k<<<50000, 64, 0, stream>>>((const i32x2*)pe2, hist, loc, boff, (const u32*)nodeQ,
                                   (const u32*)nodeKV, ea, lam, (u32*)Gf);
  gemm_final<<<782, 256, 0, stream>>>(Gf, WfT, nodeQ, bproj, rmsw, (float*)d_out);
}

// Round 11
// 543.289 us; speedup vs baseline: 1.0922x; 1.0922x over previous
//
#include <hip/hip_runtime.h>

typedef unsigned short u16;
typedef unsigned int   u32;
typedef _Float16 half8 __attribute__((ext_vector_type(8)));
typedef _Float16 half2v __attribute__((ext_vector_type(2)));
typedef float    f32x4 __attribute__((ext_vector_type(4)));
typedef unsigned int u32x4 __attribute__((ext_vector_type(4)));
typedef int      i32x2 __attribute__((ext_vector_type(2)));

#define NN 50000
#define EE 800000
#define SCALE 0.17677669529663687f
#define NB 49   // ceil(50000/1024)

// workspace layout (bytes)
#define O_WNODET   0ul          // 1536*128 f16
#define O_WFT      393216ul     // 128*512 f16
#define O_WF1      524288ul     // 128*128 f32
#define O_WF3      589824ul     // 128*128 f32
#define O_HIST     655360ul     // 50000 i32
#define O_BSUM     855360ul     // 49 i32 (inside HIST pad region)
#define O_BOFF     855616ul     // 49 i32
#define O_OFF      856064ul     // 50000 i32 (block-local exclusive scan)
#define O_CUR      1056768ul
#define O_PERM     1257472ul    // 800000 int2
#define O_NODEQ    7657472ul    // 50000*896 f16 = 89.6 MB (dst-side: q1,q2,qa,r1,r2,ra,resid)
#define O_NODEKV   97257472ul   // 50000*640 f16 = 64 MB (src-side: k1,k2,ka,vd,va)
#define O_G        161257472ul  // 50000*512 f16 ; ALSO reused as xh (50000*128 f16)
                                // during gemm_node — Gf is written only later by attn.

__device__ __forceinline__ float fin(float x){
  return (x == x && fabsf(x) < 3e38f) ? x : 0.f;
}
__device__ __forceinline__ u32 packh(float a, float b){
  union{ u32 u; _Float16 h[2]; } cv; cv.h[0]=(_Float16)a; cv.h[1]=(_Float16)b; return cv.u;
}
union H2U { u32 u; half2v h; };
__device__ __forceinline__ half2v h2(u32 u){ H2U c; c.u=u; return c.h; }

// non-temporal (no-allocate) loads for read-once streams
__device__ __forceinline__ u32x4 ntl4(const u32* p){
  return __builtin_nontemporal_load((const u32x4*)p);
}
__device__ __forceinline__ f32x4 ntlf4(const float* p){
  return __builtin_nontemporal_load((const f32x4*)p);
}
__device__ __forceinline__ i32x2 ntl2(const i32x2* p){
  return __builtin_nontemporal_load(p);
}

// ---------------- x -> f16 cast (once) + zero hist/cur (folds 2 memsets) ----------------
__global__ __launch_bounds__(256) void xcast(const float* __restrict__ x,
                                             _Float16* __restrict__ xh,
                                             int* __restrict__ hist, int* __restrict__ cur)
{
  int i = blockIdx.x*256 + threadIdx.x;       // 800000 chunks of 8
  if (i < NN){ hist[i] = 0; cur[i] = 0; }
  size_t b = (size_t)i * 8;
  float4 v0 = *(const float4*)(x + b);
  float4 v1 = *(const float4*)(x + b + 4);
  half8 h;
  h[0]=(_Float16)v0.x; h[1]=(_Float16)v0.y; h[2]=(_Float16)v0.z; h[3]=(_Float16)v0.w;
  h[4]=(_Float16)v1.x; h[5]=(_Float16)v1.y; h[6]=(_Float16)v1.z; h[7]=(_Float16)v1.w;
  *(half8*)(xh + b) = h;
}

// ---------------- weight prep ----------------
__global__ __launch_bounds__(256) void prep1(
    const float* __restrict__ Wq1, const float* __restrict__ Wq2, const float* __restrict__ Wqa,
    const float* __restrict__ Wk1, const float* __restrict__ Wk2, const float* __restrict__ Wka,
    const float* __restrict__ Wvd, const float* __restrict__ Wva, const float* __restrict__ Win,
    const float* __restrict__ Wkr1, const float* __restrict__ Wkr2, const float* __restrict__ Wkra,
    const float* __restrict__ Wproj, const float* __restrict__ Woutd, const float* __restrict__ Wouta,
    _Float16* __restrict__ WnodeT, float* __restrict__ Wf1, float* __restrict__ Wf3)
{
  int job = blockIdx.x*256 + threadIdx.x;
  if (job < 1536*128) {
    int n = job >> 7, kk = job & 127;
    int slot = n >> 7, o = n & 127;
    float val;
    if (slot==3 || slot==4 || slot==5) {
      const float* Wkr = (slot==3)?Wkr1:(slot==4)?Wkr2:Wkra;
      const float* Wq  = (slot==3)?Wq1 :(slot==4)?Wq2 :Wqa;
      int h=o>>5, j=o&31;
      float s=0.f;
      for (int c=0;c<32;c++)
        s += Wkr[(h*32+c)*32 + j] * Wq[(h*32+c)*128 + kk];
      val = s;
    } else {
      const float* W = (slot==0)?Wq1:(slot==1)?Wq2:(slot==2)?Wqa:
                       (slot==6)?Wk1:(slot==7)?Wk2:(slot==8)?Wka:
                       (slot==9)?Wvd:(slot==10)?Wva:Win;
      val = W[o*128 + kk];
    }
    WnodeT[n*128 + kk] = (_Float16)fin(val);
  } else {
    int idx = job - 1536*128;
    int which = idx >> 14;
    int r = idx & 16383;
    int o = r >> 7, v = r & 127;
    const float* Wout = which ? Wouta : Woutd;
    float s=0.f;
    for (int u=0;u<128;u++)
      s += Wproj[o*256 + which*128 + u] * Wout[u*128 + v];
    (which?Wf3:Wf1)[o*128+v] = fin(s);
  }
}

__global__ __launch_bounds__(256) void prep2(
    const float* __restrict__ Wf1, const float* __restrict__ Wf3,
    const float* __restrict__ Wvrd, const float* __restrict__ Wvra,
    _Float16* __restrict__ WfT)
{
  int job = blockIdx.x*256 + threadIdx.x;
  int o = job >> 9, kk = job & 511;
  int seg = kk >> 7, v = kk & 127;
  float val;
  if (seg==0) val = Wf1[o*128+v];
  else if (seg==2) val = Wf3[o*128+v];
  else {
    const float* Wf = (seg==1)?Wf1:Wf3;
    const float* Wv = (seg==1)?Wvrd:Wvra;
    int h=v>>5, j=v&31; float s=0.f;
    for (int c=0;c<32;c++)
      s += Wf[o*128 + h*32 + c] * Wv[(h*32+c)*32 + j];
    val = s;
  }
  WfT[o*512 + kk] = (_Float16)fin(val);
}

// ---------------- node GEMM v2 (measured 81 us) + folded edge histogram ----------------
// A from pre-cast xh (half8 loads). Epilogue: LDS transpose + coalesced half8 stores.
// hist is zeroed by xcast (prior dispatch); each of this kernel's first 800000
// threads does one edge's atomicAdd -> hist_k dispatch eliminated.
// Output split: slots 0..5 -> nodeQ cols 0..767 ; slot 11 -> nodeQ cols 768..895 (+b_in)
//               slots 6..10 -> nodeKV cols 0..639
__global__ __launch_bounds__(256) void gemm_node(
    const _Float16* __restrict__ xh, const _Float16* __restrict__ WnodeT,
    const float* __restrict__ b_in,
    _Float16* __restrict__ nodeQ, _Float16* __restrict__ nodeKV,
    const int* __restrict__ ei, int* __restrict__ hist)
{
  __shared__ _Float16 S[18432];   // 2*128*72 staging; epilogue reuses as [128][136]
  _Float16 (*As)[72] = (_Float16(*)[72])S;
  _Float16 (*Bs)[72] = (_Float16(*)[72])(S + 9216);
  int m0 = blockIdx.x * 128;
  int slot = blockIdx.y;
  int n0 = slot * 128;
  int tid = threadIdx.x;

  // folded histogram: flat thread id over grid covers all 800000 edges
  {
    int fid = (blockIdx.y * gridDim.x + blockIdx.x) * 256 + tid;
    if (fid < EE){
      int d = ei[EE + fid];
      if ((unsigned)d < (unsigned)NN) atomicAdd(&hist[d], 1);
    }
  }

  int lane = tid & 63, wave = tid >> 6;
  int lm = lane & 15, lq = lane >> 4;
  int mbase = wave*32;
  f32x4 acc[2][8];
  #pragma unroll
  for (int i=0;i<2;i++)
    #pragma unroll
    for (int j=0;j<8;j++) acc[i][j] = (f32x4){0.f,0.f,0.f,0.f};

  for (int kt=0; kt<2; kt++){
    int kk0 = kt*64;
    #pragma unroll
    for (int i=0;i<4;i++){
      int c = tid + i*256;
      int row = c >> 3, kc = (c & 7) * 8;
      int grow = m0 + row;
      half8 hv;
      if (grow < NN){
        hv = *(const half8*)(xh + (size_t)grow*128 + kk0 + kc);
      } else {
        #pragma unroll
        for (int j=0;j<8;j++) hv[j] = (_Float16)0.f;
      }
      *(half8*)&As[row][kc] = hv;
      *(half8*)&Bs[row][kc] = *(const half8*)(WnodeT + (size_t)(n0+row)*128 + kk0 + kc);
    }
    __syncthreads();
    #pragma unroll
    for (int ks=0; ks<64; ks+=32){
      half8 a0 = *(half8*)&As[mbase + lm][ks + lq*8];
      half8 a1 = *(half8*)&As[mbase + 16 + lm][ks + lq*8];
      #pragma unroll
      for (int ct=0; ct<8; ct++){
        half8 b = *(half8*)&Bs[ct*16 + lm][ks + lq*8];
        acc[0][ct] = __builtin_amdgcn_mfma_f32_16x16x32_f16(a0, b, acc[0][ct], 0,0,0);
        acc[1][ct] = __builtin_amdgcn_mfma_f32_16x16x32_f16(a1, b, acc[1][ct], 0,0,0);
      }
    }
    __syncthreads();
  }

  // epilogue: transpose via LDS, then coalesced half8 stores
  #pragma unroll
  for (int rt=0; rt<2; rt++){
    #pragma unroll
    for (int reg=0; reg<4; reg++){
      int row = mbase + rt*16 + lq*4 + reg;
      #pragma unroll
      for (int ct=0; ct<8; ct++){
        int col = ct*16 + lm;
        float bias = (slot == 11) ? b_in[col] : 0.f;
        S[row*136 + col] = (_Float16)fin(acc[rt][ct][reg] + bias);
      }
    }
  }
  __syncthreads();
  #pragma unroll
  for (int i=0;i<8;i++){
    int idx = tid + i*256;
    int row = idx >> 4, c8 = (idx & 15)*8;
    int grow = m0 + row;
    if (grow < NN){
      half8 v = *(half8*)&S[row*136 + c8];
      _Float16* dst = (slot < 6)  ? nodeQ  + (size_t)grow*896 + slot*128 + c8
                    : (slot < 11) ? nodeKV + (size_t)grow*640 + (slot-6)*128 + c8
                                  : nodeQ  + (size_t)grow*896 + 768 + c8;
      *(half8*)dst = v;
    }
  }
}

// ---------------- counting sort by dst (hist folded into gemm_node) ----------------
__global__ __launch_bounds__(1024) void scan1(const int* __restrict__ hist,
                                              int* __restrict__ loc, int* __restrict__ bsum){
  __shared__ int buf[1024];
  int i = blockIdx.x*1024 + threadIdx.x;
  int v = (i < NN) ? hist[i] : 0;
  buf[threadIdx.x] = v;
  __syncthreads();
  int xv = v;
  for (int s = 1; s < 1024; s <<= 1){
    int t = 0;
    if ((int)threadIdx.x >= s) t = buf[threadIdx.x - s];
    __syncthreads();
    xv += t;
    buf[threadIdx.x] = xv;
    __syncthreads();
  }
  if (i < NN) loc[i] = xv - v;   // block-local exclusive
  if (threadIdx.x == 1023) bsum[blockIdx.x] = xv;
}

__global__ __launch_bounds__(64) void scan2(const int* __restrict__ bsum, int* __restrict__ boff){
  int t = threadIdx.x;
  int v = (t < NB) ? bsum[t] : 0;
  int x = v;
  for (int s = 1; s < 64; s <<= 1){
    int u = __shfl_up(x, s);
    if (t >= s) x += u;
  }
  if (t < NB) boff[t] = x - v;
}

__global__ __launch_bounds__(256) void scatter_k(const int* __restrict__ ei,
                                                 const int* __restrict__ loc, const int* __restrict__ boff,
                                                 int* __restrict__ cur, int2* __restrict__ pe2){
  int e = blockIdx.x*256 + threadIdx.x;
  int d = ei[EE + e];
  if ((unsigned)d >= (unsigned)NN) return;
  int pos = loc[d] + boff[d>>10] + atomicAdd(&cur[d], 1);
  if ((unsigned)pos < (unsigned)EE) pe2[pos] = make_int2(e, ei[e]);
}

// ---------------- fused per-node attention (single dispatch) ----------------
__global__ __launch_bounds__(64, 4) void attn_k(
    const i32x2* __restrict__ pe2, const int* __restrict__ hist,
    const int* __restrict__ loc, const int* __restrict__ boff,
    const u32* __restrict__ nfQ, const u32* __restrict__ nfKV,
    const float* __restrict__ ea,
    const float* __restrict__ lamp, u32* __restrict__ G)
{
  int lane = threadIdx.x & 63;
  int node = blockIdx.x;
  if (node >= NN) return;
  int E = lane >> 4;
  int l = lane & 15;
  int h = l >> 2;
  const u32* pd = nfQ + (u32)node * 448u;

  int k = hist[node];
  if (k < 0) k = 0;
  if (k > 64) k = 64;               // Poisson(16): max ~45; guards OOB/hangs
  int o = loc[node] + boff[node>>10];
  if (o < 0) o = 0;

  // preload the node's pe2 slice: lane i holds entry i (clamped), coalesced 8B/lane
  int pe_e = 0, pe_s = 0;
  if (k > 0){
    int idxl = (lane < k) ? lane : (k-1);
    i32x2 pl = ntl2(&pe2[o + idxl]);
    pe_e = pl[0]; pe_s = pl[1];
  }

  H2U q1[4], q2[4], qa[4], r1[4], r2[4], ra[4];
  {
    u32x4 a = ntl4(pd +        l*4);
    u32x4 b = ntl4(pd +  64 + l*4);
    u32x4 c = ntl4(pd + 128 + l*4);
    q1[0].u=a[0]; q1[1].u=a[1]; q1[2].u=a[2]; q1[3].u=a[3];
    q2[0].u=b[0]; q2[1].u=b[1]; q2[2].u=b[2]; q2[3].u=b[3];
    qa[0].u=c[0]; qa[1].u=c[1]; qa[2].u=c[2]; qa[3].u=c[3];
    int rb = h*16 + (l&3)*4;
    u32x4 d = ntl4(pd + 192 + rb);
    u32x4 e = ntl4(pd + 256 + rb);
    u32x4 f = ntl4(pd + 320 + rb);
    r1[0].u=d[0]; r1[1].u=d[1]; r1[2].u=d[2]; r1[3].u=d[3];
    r2[0].u=e[0]; r2[1].u=e[1]; r2[2].u=e[2]; r2[3].u=e[3];
    ra[0].u=f[0]; ra[1].u=f[1]; ra[2].u=f[2]; ra[3].u=f[3];
  }

  H2U s1v[4], s2v[4], sav[4], s1e[4], s2e[4], sae[4];
  #pragma unroll
  for (int t=0;t<4;t++){ s1v[t].u=0; s2v[t].u=0; sav[t].u=0; s1e[t].u=0; s2e[t].u=0; sae[t].u=0; }
  float z1=0.f, z2=0.f, za=0.f;

  int iters = (k + 3) >> 2;
  for (int it=0; it<iters; it++){
    int eidx = it*4 + E;
    bool valid = eidx < k;
    int sn = __shfl(pe_s, eidx);
    int ee = __shfl(pe_e, eidx);
    if (!valid){ sn = 0; ee = 0; }
    if ((unsigned)sn >= (unsigned)NN) sn = 0;
    if ((unsigned)ee >= (unsigned)EE) ee = 0;
    const u32* ps = nfKV + (u32)sn * 320u + (u32)(l*4);
    u32x4 K1 = *(const u32x4*)(ps);
    u32x4 K2 = *(const u32x4*)(ps + 64);
    u32x4 KA = *(const u32x4*)(ps + 128);
    u32x4 VD = *(const u32x4*)(ps + 192);
    u32x4 VA = *(const u32x4*)(ps + 256);
    f32x4 ef0 = ntlf4(ea + (size_t)ee*32 + (l&3)*8);
    f32x4 ef1 = ntlf4(ea + (size_t)ee*32 + (l&3)*8 + 4);
    half2v e0 = {(_Float16)ef0[0], (_Float16)ef0[1]};
    half2v e1 = {(_Float16)ef0[2], (_Float16)ef0[3]};
    half2v e2 = {(_Float16)ef1[0], (_Float16)ef1[1]};
    half2v e3 = {(_Float16)ef1[2], (_Float16)ef1[3]};

    half2v p1h = q1[0].h*h2(K1[0]) + q1[1].h*h2(K1[1]) + q1[2].h*h2(K1[2]) + q1[3].h*h2(K1[3])
               + r1[0].h*e0 + r1[1].h*e1 + r1[2].h*e2 + r1[3].h*e3;
    half2v p2h = q2[0].h*h2(K2[0]) + q2[1].h*h2(K2[1]) + q2[2].h*h2(K2[2]) + q2[3].h*h2(K2[3])
               + r2[0].h*e0 + r2[1].h*e1 + r2[2].h*e2 + r2[3].h*e3;
    half2v pah = qa[0].h*h2(KA[0]) + qa[1].h*h2(KA[1]) + qa[2].h*h2(KA[2]) + qa[3].h*h2(KA[3])
               + ra[0].h*e0 + ra[1].h*e1 + ra[2].h*e2 + ra[3].h*e3;

    // reduce over the 4 lanes of this head (xor 1,2)
    H2U c1, c2, c3, t;
    c1.h = p1h; c2.h = p2h; c3.h = pah;
    t.u = __shfl_xor(c1.u, 1); c1.h += t.h;
    t.u = __shfl_xor(c2.u, 1); c2.h += t.h;
    t.u = __shfl_xor(c3.u, 1); c3.h += t.h;
    t.u = __shfl_xor(c1.u, 2); c1.h += t.h;
    t.u = __shfl_xor(c2.u, 2); c2.h += t.h;
    t.u = __shfl_xor(c3.u, 2); c3.h += t.h;
    float p1 = (float)c1.h[0] + (float)c1.h[1];
    float p2 = (float)c2.h[0] + (float)c2.h[1];
    float pa = (float)c3.h[0] + (float)c3.h[1];

    float w1 = valid ? __expf(p1*SCALE) : 0.f;
    float w2 = valid ? __expf(p2*SCALE) : 0.f;
    float wa = valid ? __expf(pa*SCALE) : 0.f;
    _Float16 w1f = (_Float16)w1, w2f = (_Float16)w2, waf = (_Float16)wa;
    half2v w1h = {w1f, w1f}, w2h = {w2f, w2f}, wah = {waf, waf};

    s1v[0].h += w1h*h2(VD[0]); s1v[1].h += w1h*h2(VD[1]); s1v[2].h += w1h*h2(VD[2]); s1v[3].h += w1h*h2(VD[3]);
    s2v[0].h += w2h*h2(VD[0]); s2v[1].h += w2h*h2(VD[1]); s2v[2].h += w2h*h2(VD[2]); s2v[3].h += w2h*h2(VD[3]);
    sav[0].h += wah*h2(VA[0]); sav[1].h += wah*h2(VA[1]); sav[2].h += wah*h2(VA[2]); sav[3].h += wah*h2(VA[3]);
    s1e[0].h += w1h*e0; s1e[1].h += w1h*e1; s1e[2].h += w1h*e2; s1e[3].h += w1h*e3;
    s2e[0].h += w2h*e0; s2e[1].h += w2h*e1; s2e[2].h += w2h*e2; s2e[3].h += w2h*e3;
    sae[0].h += wah*e0; sae[1].h += wah*e1; sae[2].h += wah*e2; sae[3].h += wah*e3;
    z1 += w1; z2 += w2; za += wa;
  }

  // cross-slot reduction (xor 16, 32)
  #pragma unroll
  for (int s=16; s<=32; s<<=1){
    H2U t;
    #pragma unroll
    for (int j=0;j<4;j++){
      t.u = __shfl_xor(s1v[j].u, s); s1v[j].h += t.h;
      t.u = __shfl_xor(s2v[j].u, s); s2v[j].h += t.h;
      t.u = __shfl_xor(sav[j].u, s); sav[j].h += t.h;
      t.u = __shfl_xor(s1e[j].u, s); s1e[j].h += t.h;
      t.u = __shfl_xor(s2e[j].u, s); s2e[j].h += t.h;
      t.u = __shfl_xor(sae[j].u, s); sae[j].h += t.h;
    }
    z1 += __shfl_xor(z1, s); z2 += __shfl_xor(z2, s); za += __shfl_xor(za, s);
  }

  if (E == 0){
    float lamv = lamp[0];
    float i1 = 1.f/(z1+1e-16f), i2 = 1.f/(z2+1e-16f), ia = 1.f/(za+1e-16f);
    u32 gb = (u32)node*256u;
    int rb = h*16 + (l&3)*4;
    #pragma unroll
    for (int t=0;t<4;t++){
      float d0 = fin((float)s1v[t].h[0]*i1 - lamv*((float)s2v[t].h[0]*i2));
      float d1 = fin((float)s1v[t].h[1]*i1 - lamv*((float)s2v[t].h[1]*i2));
      G[gb + l*4 + t] = packh(d0, d1);
      float e0v = fin((float)s1e[t].h[0]*i1 - lamv*((float)s2e[t].h[0]*i2));
      float e1v = fin((float)s1e[t].h[1]*i1 - lamv*((float)s2e[t].h[1]*i2));
      G[gb + 64 + rb + t] = packh(e0v, e1v);
      G[gb + 128 + l*4 + t] = packh(fin((float)sav[t].h[0]*ia), fin((float)sav[t].h[1]*ia));
      G[gb + 192 + rb + t] = packh(fin((float)sae[t].h[0]*ia), fin((float)sae[t].h[1]*ia));
    }
  }
}

// ---------------- final GEMM + bias + residual + RMSNorm ----------------
// M-tile 64; epilogue stages normalized rows in LDS then stores coalesced f32x4.
__global__ __launch_bounds__(256) void gemm_final(
    const _Float16* __restrict__ Gf, const _Float16* __restrict__ WfT,
    const _Float16* __restrict__ nodeQ,
    const float* __restrict__ bproj, const float* __restrict__ rmsw,
    float* __restrict__ out)
{
  __shared__ char SS[34816];                         // As+Bs staging; epilogue f32 [64][132]
  _Float16 (*As)[72] = (_Float16(*)[72])SS;          // 64*72*2  = 9216 B
  _Float16 (*Bs)[72] = (_Float16(*)[72])(SS + 9216); // 128*72*2 = 18432 B
  float* Sf = (float*)SS;                            // 64*132*4 = 33792 B (reuse)
  __shared__ float bS[128], rS[128];
  int m0 = blockIdx.x * 64;
  int tid = threadIdx.x;
  int lane = tid & 63, wave = tid >> 6;
  int lm = lane & 15, lq = lane >> 4;
  int mbase = wave*16;
  if (tid < 128){ bS[tid] = bproj[tid]; rS[tid] = rmsw[tid]; }
  f32x4 acc[8];
  #pragma unroll
  for (int j=0;j<8;j++) acc[j] = (f32x4){0.f,0.f,0.f,0.f};

  for (int kt=0; kt<8; kt++){
    int kk0 = kt*64;
    #pragma unroll
    for (int i=0;i<2;i++){
      int c = tid + i*256;
      int row = c >> 3, kc = (c & 7) * 8;
      int grow = m0 + row;
      half8 av;
      if (grow < NN){
        av = *(const half8*)(Gf + (size_t)grow*512 + kk0 + kc);
      } else {
        #pragma unroll
        for (int j=0;j<8;j++) av[j] = (_Float16)0.f;
      }
      *(half8*)&As[row][kc] = av;
    }
    #pragma unroll
    for (int i=0;i<4;i++){
      int c = tid + i*256;
      int row = c >> 3, kc = (c & 7) * 8;
      *(half8*)&Bs[row][kc] = *(const half8*)(WfT + (size_t)row*512 + kk0 + kc);
    }
    __syncthreads();
    #pragma unroll
    for (int ks=0; ks<64; ks+=32){
      half8 a0 = *(half8*)&As[mbase + lm][ks + lq*8];
      #pragma unroll
      for (int ct=0; ct<8; ct++){
        half8 b = *(half8*)&Bs[ct*16 + lm][ks + lq*8];
        acc[ct] = __builtin_amdgcn_mfma_f32_16x16x32_f16(a0, b, acc[ct], 0,0,0);
      }
    }
    __syncthreads();
  }
  // epilogue: normalize into LDS, then coalesced f32x4 stores
  #pragma unroll
  for (int reg=0; reg<4; reg++){
    int rowl = mbase + lq*4 + reg;
    int row = m0 + rowl;
    bool ok = row < NN;
    float vals[8]; float ss = 0.f;
    #pragma unroll
    for (int ct=0; ct<8; ct++){
      int col = ct*16 + lm;
      float R = ok ? (float)nodeQ[(size_t)row*896 + 768 + col] : 0.f;
      float v = fin(acc[ct][reg] + bS[col] + R);
      vals[ct] = v; ss += v*v;
    }
    #pragma unroll
    for (int sh=1; sh<16; sh<<=1) ss += __shfl_xor(ss, sh);
    float rstd = rsqrtf(ss*(1.0f/128.f) + 1e-6f);
    #pragma unroll
    for (int ct=0; ct<8; ct++){
      int col = ct*16 + lm;
      Sf[rowl*132 + col] = fin(vals[ct]*rstd*rS[col]);
    }
  }
  __syncthreads();
  #pragma unroll
  for (int i=0;i<8;i++){
    int idx = tid + i*256;
    int rowl = idx >> 5, c4 = (idx & 31) * 4;
    int grow = m0 + rowl;
    if (grow < NN){
      f32x4 v = *(f32x4*)&Sf[rowl*132 + c4];
      *(f32x4*)(out + (size_t)grow*128 + c4) = v;
    }
  }
}

extern "C" void kernel_launch(void* const* d_in, const int* in_sizes, int n_in,
                              void* d_out, int out_size, void* d_ws, size_t ws_size,
                              hipStream_t stream)
{
  char* w = (char*)d_ws;
  _Float16* WnodeT = (_Float16*)(w + O_WNODET);
  _Float16* WfT    = (_Float16*)(w + O_WFT);
  float*    Wf1    = (float*)(w + O_WF1);
  float*    Wf3    = (float*)(w + O_WF3);
  int*      hist   = (int*)(w + O_HIST);
  int*      bsum   = (int*)(w + O_BSUM);
  int*      boff   = (int*)(w + O_BOFF);
  int*      loc    = (int*)(w + O_OFF);
  int*      cur    = (int*)(w + O_CUR);
  int2*     pe2    = (int2*)(w + O_PERM);
  _Float16* nodeQ  = (_Float16*)(w + O_NODEQ);
  _Float16* nodeKV = (_Float16*)(w + O_NODEKV);
  _Float16* Gf     = (_Float16*)(w + O_G);
  _Float16* xh     = (_Float16*)(w + O_G);   // reused region: consumed before Gf is written

  const float* x     = (const float*)d_in[0];
  const int*   ei    = (const int*)d_in[1];
  const float* ea    = (const float*)d_in[2];
  const float* Wq1   = (const float*)d_in[3];
  const float* Wq2   = (const float*)d_in[4];
  const float* Wk1   = (const float*)d_in[5];
  const float* Wk2   = (const float*)d_in[6];
  const float* Wvd   = (const float*)d_in[7];
  const float* Wkr1  = (const float*)d_in[8];
  const float* Wkr2  = (const float*)d_in[9];
  const float* Wvrd  = (const float*)d_in[10];
  const float* Woutd = (const float*)d_in[11];
  const float* lam   = (const float*)d_in[12];
  const float* Wqa   = (const float*)d_in[13];
  const float* Wka   = (const float*)d_in[14];
  const float* Wva   = (const float*)d_in[15];
  const float* Wkra  = (const float*)d_in[16];
  const float* Wvra  = (const float*)d_in[17];
  const float* Wouta = (const float*)d_in[18];
  const float* Wproj = (const float*)d_in[19];
  const float* bproj = (const float*)d_in[20];
  const float* Win   = (const float*)d_in[21];
  const float* b_in  = (const float*)d_in[22];
  const float* rmsw  = (const float*)d_in[23];

  xcast<<<3125, 256, 0, stream>>>(x, xh, hist, cur);
  prep1<<<896, 256, 0, stream>>>(Wq1,Wq2,Wqa, Wk1,Wk2,Wka, Wvd,Wva,Win,
                                 Wkr1,Wkr2,Wkra, Wproj,Woutd,Wouta,
                                 WnodeT, Wf1, Wf3);
  prep2<<<256, 256, 0, stream>>>(Wf1, Wf3, Wvrd, Wvra, WfT);
  gemm_node<<<dim3(391,12), 256, 0, stream>>>(xh, WnodeT, b_in, nodeQ, nodeKV, ei, hist);
  scan1<<<NB, 1024, 0, stream>>>(hist, loc, bsum);
  scan2<<<1, 64, 0, stream>>>(bsum, boff);
  scatter_k<<<3125, 256, 0, stream>>>(ei, loc, boff, cur, pe2);
  attn_k<<<50000, 64, 0, stream>>>((const i32x2*)pe2, hist, loc, boff, (const u32*)nodeQ,
                                   (const u32*)nodeKV, ea, lam, (u32*)Gf);
  gemm_final<<<782, 256, 0, stream>>>(Gf, WfT, nodeQ, bproj, rmsw, (float*)d_out);
}